// Round 10
// baseline (138.705 us; speedup 1.0000x reference)
//
#include <hip/hip_runtime.h>
#include <stdint.h>

typedef _Float16 f16;
typedef __attribute__((ext_vector_type(8))) _Float16 f16x8;
typedef __attribute__((ext_vector_type(4))) float    f32x4;

constexpr int NB = 16384;

// packed-weight regions (f16 elem offsets). chunk = 512 f16 covering 16 cols x 32 k:
// elem ((nt*KB + kb)*64 + g*16 + rr)*8 + q  <->  W^T[col = nt*16+rr][k = kb*32+g*8+q]
constexpr int OFF_CW1  = 0;        // NT=16, KB=15  (cW1: 464x256)
constexpr int OFF_CW2  = 122880;   // NT=8,  KB=8   (cW2: 256x128)
constexpr int OFF_COW  = 155648;   // NT=32, KB=4   (coW: 128x464, pad 512)
constexpr int OFF_EW1G = 221184;   // NT=72, KB=15  (expW1 4x(464x256) + gateW 12 cols, pad 1152)
constexpr int OFF_EW2  = 774144;   // NT=32, KB=8   (expW2 4x(256x128))
constexpr int PACK_TOTAL = 905216;

__device__ __forceinline__ void g2l16(const void* g, void* l) {
    __builtin_amdgcn_global_load_lds(
        (__attribute__((address_space(1))) void*)(void*)g,
        (__attribute__((address_space(3))) void*)l, 16, 0, 0);
}

// ---------------------------------------------------------------------------
// K0: pack weights -> chunk layout. One wave per 512-f16 chunk; per q-step the
// wave reads 16 consecutive f32 per g-group (coalesced); 16B-coalesced writes.
// ---------------------------------------------------------------------------
__global__ __launch_bounds__(256)
void k_pack(const float* __restrict__ cW1, const float* __restrict__ cW2,
            const float* __restrict__ coW, const float* __restrict__ expW1,
            const float* __restrict__ expW2, const float* __restrict__ gateW,
            f16* __restrict__ wp)
{
    const int lane = threadIdx.x & 63;
    const int chunk = (blockIdx.x * 256 + threadIdx.x) >> 6;
    if (chunk >= PACK_TOTAL / 512) return;
    const int off = chunk * 512;
    const int rr = lane & 15, gg = lane >> 4;
    float v[8];
    if (off < OFF_CW2) {
        const int cl = off / 512, nt = cl / 15, kb = cl % 15;
        const int n = nt * 16 + rr, k0 = kb * 32 + gg * 8;
#pragma unroll
        for (int q = 0; q < 8; ++q) { const int k = k0 + q; v[q] = (k < 464) ? cW1[k * 256 + n] : 0.f; }
    } else if (off < OFF_COW) {
        const int cl = (off - OFF_CW2) / 512, nt = cl / 8, kb = cl % 8;
        const int n = nt * 16 + rr, k0 = kb * 32 + gg * 8;
#pragma unroll
        for (int q = 0; q < 8; ++q) v[q] = cW2[(k0 + q) * 128 + n];
    } else if (off < OFF_EW1G) {
        const int cl = (off - OFF_COW) / 512, nt = cl / 4, kb = cl % 4;
        const int n = nt * 16 + rr, k0 = kb * 32 + gg * 8;
#pragma unroll
        for (int q = 0; q < 8; ++q) v[q] = (n < 464) ? coW[(k0 + q) * 464 + n] : 0.f;
    } else if (off < OFF_EW2) {
        const int cl = (off - OFF_EW1G) / 512, nt = cl / 15, kb = cl % 15;
        const int n = nt * 16 + rr, k0 = kb * 32 + gg * 8;
        if (n < 1024) {
            const int e = n >> 8, nn = n & 255;
#pragma unroll
            for (int q = 0; q < 8; ++q) { const int k = k0 + q;
                v[q] = (k < 464) ? expW1[((size_t)e * 464 + k) * 256 + nn] : 0.f; }
        } else if (n < 1036) {
            const int c = n - 1024;
#pragma unroll
            for (int q = 0; q < 8; ++q) { const int k = k0 + q;
                v[q] = (k < 464) ? gateW[((size_t)(c >> 2) * 464 + k) * 4 + (c & 3)] : 0.f; }
        } else {
#pragma unroll
            for (int q = 0; q < 8; ++q) v[q] = 0.f;
        }
    } else {
        const int cl = (off - OFF_EW2) / 512, nt = cl / 8, kb = cl % 8;
        const int n = nt * 16 + rr, k0 = kb * 32 + gg * 8;
        const int e = n >> 7, nn = n & 127;
#pragma unroll
        for (int q = 0; q < 8; ++q) v[q] = expW2[((size_t)e * 256 + q + k0) * 128 + nn];
    }
    f16x8 o;
#pragma unroll
    for (int q = 0; q < 8; ++q) o[q] = (f16)v[q];
    *(f16x8*)(wp + (size_t)off + lane * 8) = o;
}

// ---------------------------------------------------------------------------
// K1: gather + cont + fm; writes x packed [rowtile16][kb15][g][rr][q8].
// ---------------------------------------------------------------------------
__global__ __launch_bounds__(256)
void k_build(const int* __restrict__ disc, const float* __restrict__ cf,
             const float* __restrict__ e0p, const float* __restrict__ e1p,
             const float* __restrict__ e2p, const float* __restrict__ e3p,
             const float* __restrict__ e4p, const float* __restrict__ e5p,
             const float* __restrict__ e6p, const float* __restrict__ e7p,
             const float* __restrict__ contW, const float* __restrict__ contB,
             const float* __restrict__ fmW,
             f16* __restrict__ xpk, float* __restrict__ fm)
{
    __shared__ f16   xs[64][480];
    __shared__ float cfs[64][68];
    __shared__ float ctw[64][64];
    __shared__ float fmw[4640];
    __shared__ float xes[64][10];
    __shared__ const float* stabs[8];

    const int t = threadIdx.x;
    const long r0 = (long)blockIdx.x * 64;
    if (t == 0) {
        stabs[0] = e0p; stabs[1] = e1p; stabs[2] = e2p; stabs[3] = e3p;
        stabs[4] = e4p; stabs[5] = e5p; stabs[6] = e6p; stabs[7] = e7p;
    }
    __syncthreads();

    for (int i = t; i < 64 * 16; i += 256) xs[i >> 4][464 + (i & 15)] = (f16)0.f;
    for (int i = t; i < 64 * 16; i += 256) {
        const int r = i >> 4, q = i & 15;
        const float4 v = *(const float4*)(cf + (r0 + r) * 64 + q * 4);
        cfs[r][q * 4] = v.x; cfs[r][q * 4 + 1] = v.y; cfs[r][q * 4 + 2] = v.z; cfs[r][q * 4 + 3] = v.w;
    }
    for (int i = t; i < 1024; i += 256) {
        const int k = i >> 4, c4 = (i & 15) * 4;
        *(float4*)&ctw[k][c4] = *(const float4*)(contW + k * 64 + c4);
    }
    for (int i = t; i < 4640; i += 256) fmw[i] = fmW[i];
    for (int p = t; p < 512; p += 256) {
        const int r = p >> 3, tab = p & 7;
        const long fi = disc[(r0 + r) * 8 + tab];
        const float* src = stabs[tab] + fi * 50;
        f16* dst = &xs[r][tab * 50];
#pragma unroll
        for (int q = 0; q < 25; ++q) {
            const float2 v = *(const float2*)(src + q * 2);
            dst[q * 2] = (f16)v.x; dst[q * 2 + 1] = (f16)v.y;
        }
    }
    __syncthreads();
    for (int i = t; i < 4096; i += 256) {          // cont -> cols 400..463
        const int r = i >> 6, c = i & 63;
        float a = contB[c];
#pragma unroll 8
        for (int k = 0; k < 64; ++k) a = fmaf(cfs[r][k], ctw[k][c], a);
        xs[r][400 + c] = (f16)fmaxf(a, 0.f);
    }
    __syncthreads();
    for (int i = t; i < 640; i += 256) {           // xe = x @ fmW
        const int r = i / 10, jj = i - (i / 10) * 10;
        float a = 0.f;
        for (int d = 0; d < 464; ++d) a = fmaf((float)xs[r][d], fmw[d * 10 + jj], a);
        xes[r][jj] = a;
    }
    __syncthreads();
    if (t < 64) {
        float s = 0.f, ss = 0.f;
#pragma unroll
        for (int j = 0; j < 10; ++j) { const float v = xes[t][j]; s += v; ss += v * v; }
        fm[r0 + t] = 0.5f * (s * s - ss);
    }
    for (int si = t; si < 3840; si += 256) {       // packed write
        const int rt = si / 960, rem = si - rt * 960;
        const int kb = rem >> 6, slot = rem & 63;
        const int gg = slot >> 4, rr2 = slot & 15;
        *(f16x8*)(xpk + ((size_t)(blockIdx.x * 4 + rt) * 15 + kb) * 512 + slot * 8)
            = *(const f16x8*)&xs[rt * 16 + rr2][kb * 32 + gg * 8];
    }
}

// ---------------------------------------------------------------------------
// counted-vmcnt triple-buffered GEMM pipeline. 256 thr = 4 waves (2M x 2N),
// BM=BN=128. Per slab per wave: 4 g2l16 (A:2, B:2). vmcnt(4) mid-loop.
// ---------------------------------------------------------------------------
template<int KB>
__device__ __forceinline__ void gemm_pipe(
    const f16* __restrict__ Apk, size_t ach0,
    const f16* __restrict__ Bpk, int nt0,
    f16* lA, f16* lB, f32x4 (&acc)[4][4],
    int wave, int lane, int wm, int wn, int g, int rr)
{
    auto issue = [&](int kb) {
        const int buf = kb % 3;
#pragma unroll
        for (int h2 = 0; h2 < 2; ++h2) {
            const int rt = 2 * wave + h2;
            g2l16(Apk + (ach0 + (size_t)rt * KB + kb) * 512 + lane * 8,
                  lA + (size_t)buf * 4096 + rt * 512);
            g2l16(Bpk + ((size_t)(nt0 + rt) * KB + kb) * 512 + lane * 8,
                  lB + (size_t)buf * 4096 + rt * 512);
        }
    };
    issue(0); issue(1);
#pragma unroll
    for (int kb = 0; kb < KB; ++kb) {
        if (kb < KB - 1) asm volatile("s_waitcnt vmcnt(4)" ::: "memory");
        else             asm volatile("s_waitcnt vmcnt(0)" ::: "memory");
        __builtin_amdgcn_s_barrier();
        __builtin_amdgcn_sched_barrier(0);
        if (kb + 2 < KB) issue(kb + 2);
        const f16* A_ = lA + (size_t)(kb % 3) * 4096;
        const f16* B_ = lB + (size_t)(kb % 3) * 4096;
        f16x8 bf[4];
#pragma unroll
        for (int j = 0; j < 4; ++j)
            bf[j] = *(const f16x8*)(B_ + ((wn * 4 + j) * 64 + g * 16 + rr) * 8);
#pragma unroll
        for (int i = 0; i < 4; ++i) {
            const f16x8 af = *(const f16x8*)(A_ + ((wm * 4 + i) * 64 + g * 16 + rr) * 8);
#pragma unroll
            for (int j = 0; j < 4; ++j)
                acc[i][j] = __builtin_amdgcn_mfma_f32_16x16x32_f16(af, bf[j], acc[i][j], 0, 0, 0);
        }
    }
    __syncthreads();
}

#define GEMM_PRE() \
    __shared__ __align__(16) f16 lbuf[24576]; \
    const int t = threadIdx.x, lane = t & 63, wave = t >> 6; \
    const int wm = wave >> 1, wn = wave & 1, g = lane >> 4, rr = lane & 15; \
    const int by = blockIdx.y, ct = blockIdx.x; (void)ct; (void)t; \
    f32x4 acc[4][4] = {};

// ---------------------------------------------------------------------------
__global__ __launch_bounds__(256)
void k_c1(const f16* __restrict__ wp, const f16* __restrict__ xpk,
          const float* __restrict__ cb1, f16* __restrict__ c1pk)
{
    GEMM_PRE();
    gemm_pipe<15>(xpk, (size_t)by * 120, wp + OFF_CW1, ct * 8,
                  lbuf, lbuf + 12288, acc, wave, lane, wm, wn, g, rr);
    const int rowb = by * 128 + wm * 64;
#pragma unroll
    for (int j = 0; j < 4; ++j) {
        const int col = ct * 128 + wn * 64 + j * 16 + rr;
        const float bv = cb1[col];
        const int kbo = col >> 5, go = (col >> 3) & 3, qo = col & 7;
#pragma unroll
        for (int i = 0; i < 4; ++i)
#pragma unroll
            for (int rg = 0; rg < 4; ++rg) {
                const int row = rowb + i * 16 + g * 4 + rg;
                c1pk[(((size_t)(row >> 4) * 8 + kbo) * 64 + go * 16 + (row & 15)) * 8 + qo]
                    = (f16)fmaxf(acc[i][j][rg] + bv, 0.f);
            }
    }
}

__global__ __launch_bounds__(256)
void k_c2(const f16* __restrict__ wp, const f16* __restrict__ c1pk,
          const float* __restrict__ cb2, f16* __restrict__ c2pk)
{
    GEMM_PRE();
    gemm_pipe<8>(c1pk, (size_t)by * 64, wp + OFF_CW2, 0,
                 lbuf, lbuf + 12288, acc, wave, lane, wm, wn, g, rr);
    const int rowb = by * 128 + wm * 64;
#pragma unroll
    for (int j = 0; j < 4; ++j) {
        const int col = wn * 64 + j * 16 + rr;
        const float bv = cb2[col];
        const int kbo = col >> 5, go = (col >> 3) & 3, qo = col & 7;
#pragma unroll
        for (int i = 0; i < 4; ++i)
#pragma unroll
            for (int rg = 0; rg < 4; ++rg) {
                const int row = rowb + i * 16 + g * 4 + rg;
                c2pk[(((size_t)(row >> 4) * 4 + kbo) * 64 + go * 16 + (row & 15)) * 8 + qo]
                    = (f16)fmaxf(acc[i][j][rg] + bv, 0.f);
            }
    }
}

__global__ __launch_bounds__(256)
void k_h(const f16* __restrict__ wp, const f16* __restrict__ c2pk,
         const float* __restrict__ cob, const float* __restrict__ fm,
         f16* __restrict__ xpk)
{
    GEMM_PRE();
    gemm_pipe<4>(c2pk, (size_t)by * 32, wp + OFF_COW, ct * 8,
                 lbuf, lbuf + 12288, acc, wave, lane, wm, wn, g, rr);
    // stage this block's x tile (32 chunks) into lbuf; kbl == wave (uniform)
    const int ct4 = ct * 4;
    for (int c = wave; c < 32; c += 4) {
        const int rt_l = c >> 2, kbl = c & 3;
        if (ct4 + kbl < 15)
            g2l16(xpk + ((size_t)(by * 8 + rt_l) * 15 + ct4 + kbl) * 512 + lane * 8,
                  lbuf + (size_t)c * 512);
    }
    asm volatile("s_waitcnt vmcnt(0)" ::: "memory");
    __syncthreads();
    const int rowb = by * 128 + wm * 64;
#pragma unroll
    for (int j = 0; j < 4; ++j) {
        const int col = ct * 128 + wn * 64 + j * 16 + rr;
        if (col < 464) {
            const float bv = cob[col];
            const int kbl = (col >> 5) & 3, go = (col >> 3) & 3, qo = col & 7;
#pragma unroll
            for (int i = 0; i < 4; ++i)
#pragma unroll
                for (int rg = 0; rg < 4; ++rg) {
                    const int row = rowb + i * 16 + g * 4 + rg;
                    const int cc = (wm * 4 + i) * 4 + kbl;
                    const float xv = (float)lbuf[((size_t)cc * 64 + go * 16 + (g * 4 + rg)) * 8 + qo];
                    const float hv = acc[i][j][rg] + bv + xv + fm[row];
                    xpk[(((size_t)(row >> 4) * 15 + (col >> 5)) * 64 + go * 16 + (row & 15)) * 8 + qo]
                        = (f16)hv;
                }
        }
    }
}

__global__ __launch_bounds__(256)
void k_e1(const f16* __restrict__ wp, const f16* __restrict__ xpk,
          const float* __restrict__ expb1, const float* __restrict__ gateB,
          f16* __restrict__ e1pk, float* __restrict__ gates)
{
    GEMM_PRE();
    gemm_pipe<15>(xpk, (size_t)by * 120, wp + OFF_EW1G, ct * 8,
                  lbuf, lbuf + 12288, acc, wave, lane, wm, wn, g, rr);
    const int rowb = by * 128 + wm * 64;
    if (ct < 8) {
#pragma unroll
        for (int j = 0; j < 4; ++j) {
            const int col = ct * 128 + wn * 64 + j * 16 + rr;
            const int e = col >> 8, cl = col & 255;
            const float bv = expb1[col];
            const int kbo = cl >> 5, go = (cl >> 3) & 3, qo = cl & 7;
            f16* dst = e1pk + (size_t)e * NB * 256;
#pragma unroll
            for (int i = 0; i < 4; ++i)
#pragma unroll
                for (int rg = 0; rg < 4; ++rg) {
                    const int row = rowb + i * 16 + g * 4 + rg;
                    dst[(((size_t)(row >> 4) * 8 + kbo) * 64 + go * 16 + (row & 15)) * 8 + qo]
                        = (f16)fmaxf(acc[i][j][rg] + bv, 0.f);
                }
        }
    } else if (wn == 0) {   // gate logits live in frag j==0 (cols 1024..1039)
        const float gb = (rr < 12) ? gateB[rr] : 0.f;
#pragma unroll
        for (int i = 0; i < 4; ++i)
#pragma unroll
            for (int rg = 0; rg < 4; ++rg) {
                const float v = acc[i][0][rg] + gb;
                float m = fmaxf(v, __shfl_xor(v, 1, 64));
                m = fmaxf(m, __shfl_xor(m, 2, 64));
                const float p = __expf(v - m);
                float s = p + __shfl_xor(p, 1, 64);
                s += __shfl_xor(s, 2, 64);
                if (rr < 12) {
                    const long row = rowb + i * 16 + g * 4 + rg;
                    gates[row * 12 + rr] = p / s;
                }
            }
    }
}

__global__ __launch_bounds__(256)
void k_e2(const f16* __restrict__ wp, const f16* __restrict__ e1pk,
          const float* __restrict__ expb2, const float* __restrict__ taskW,
          const float* __restrict__ gates, float* __restrict__ part)
{
    GEMM_PRE();
    __shared__ float sh_s[2][2][64][3];
    const int z = blockIdx.z;
    gemm_pipe<8>(e1pk + (size_t)z * NB * 256, (size_t)by * 64, wp + OFF_EW2, z * 8,
                 lbuf, lbuf + 12288, acc, wave, lane, wm, wn, g, rr);
    float tws[3][4], bj[4];
#pragma unroll
    for (int j = 0; j < 4; ++j) {
        const int col = wn * 64 + j * 16 + rr;
        bj[j] = expb2[z * 128 + col];
#pragma unroll
        for (int tt = 0; tt < 3; ++tt) tws[tt][j] = taskW[tt * 128 + col];
    }
#pragma unroll
    for (int i = 0; i < 4; ++i)
#pragma unroll
        for (int rg = 0; rg < 4; ++rg) {
            float p0 = 0.f, p1 = 0.f, p2 = 0.f;
#pragma unroll
            for (int j = 0; j < 4; ++j) {
                const float v = acc[i][j][rg] + bj[j];
                p0 = fmaf(v, tws[0][j], p0);
                p1 = fmaf(v, tws[1][j], p1);
                p2 = fmaf(v, tws[2][j], p2);
            }
#pragma unroll
            for (int off = 1; off < 16; off <<= 1) {
                p0 += __shfl_xor(p0, off, 64);
                p1 += __shfl_xor(p1, off, 64);
                p2 += __shfl_xor(p2, off, 64);
            }
            if (rr == 0) {
                const int rl = i * 16 + g * 4 + rg;
                sh_s[wm][wn][rl][0] = p0; sh_s[wm][wn][rl][1] = p1; sh_s[wm][wn][rl][2] = p2;
            }
        }
    __syncthreads();
    for (int idx = t; idx < 128 * 3; idx += 256) {
        const int rl = idx / 3, tt = idx - rl * 3;
        const int wmm = rl >> 6, r2 = rl & 63;
        const float s = sh_s[wmm][0][r2][tt] + sh_s[wmm][1][r2][tt];
        const long row = (long)by * 128 + rl;
        part[((size_t)z * NB + row) * 3 + tt] = gates[row * 12 + tt * 4 + z] * s;
    }
}

__global__ __launch_bounds__(256)
void k_final(const float* __restrict__ part, const float* __restrict__ taskB,
             const float* __restrict__ logv, float* __restrict__ out)
{
    const int idx = blockIdx.x * 256 + threadIdx.x;
    if (idx < NB * 3) {
        const int row = idx / 3, tt = idx - row * 3;
        out[idx] = part[(size_t)row * 3 + tt] +
                   part[(size_t)NB * 3 + row * 3 + tt] +
                   part[(size_t)NB * 6 + row * 3 + tt] +
                   part[(size_t)NB * 9 + row * 3 + tt] + taskB[tt];
    }
    if (idx < 3) out[(size_t)NB * 3 + idx] = logv[idx];
}

// ---------------------------------------------------------------------------
extern "C" void kernel_launch(void* const* d_in, const int* in_sizes, int n_in,
                              void* d_out, int out_size, void* d_ws, size_t ws_size,
                              hipStream_t stream)
{
    (void)in_sizes; (void)n_in; (void)out_size; (void)ws_size;

    const int*   disc  = (const int*)  d_in[0];
    const float* cf    = (const float*)d_in[1];
    const float* emb0  = (const float*)d_in[2];
    const float* emb1  = (const float*)d_in[3];
    const float* emb2  = (const float*)d_in[4];
    const float* emb3  = (const float*)d_in[5];
    const float* emb4  = (const float*)d_in[6];
    const float* emb5  = (const float*)d_in[7];
    const float* emb6  = (const float*)d_in[8];
    const float* emb7  = (const float*)d_in[9];
    const float* contW = (const float*)d_in[10];
    const float* contB = (const float*)d_in[11];
    const float* fmW   = (const float*)d_in[12];
    const float* cW1   = (const float*)d_in[13];
    const float* cb1   = (const float*)d_in[14];
    const float* cW2   = (const float*)d_in[15];
    const float* cb2   = (const float*)d_in[16];
    const float* coW   = (const float*)d_in[17];
    const float* cob   = (const float*)d_in[18];
    const float* expW1 = (const float*)d_in[19];
    const float* expb1 = (const float*)d_in[20];
    const float* expW2 = (const float*)d_in[21];
    const float* expb2 = (const float*)d_in[22];
    const float* gateW = (const float*)d_in[23];
    const float* gateB = (const float*)d_in[24];
    const float* taskW = (const float*)d_in[25];
    const float* taskB = (const float*)d_in[26];
    const float* logv  = (const float*)d_in[27];

    char* w = (char*)d_ws;
    f16* wp     = (f16*)w;   w += (size_t)PACK_TOTAL * 2;
    f16* xpk    = (f16*)w;   w += (size_t)NB * 480 * 2;
    f16* c1pk   = (f16*)w;   w += (size_t)NB * 256 * 2;
    f16* c2pk   = (f16*)w;   w += (size_t)NB * 128 * 2;
    f16* e1pk   = (f16*)w;   w += (size_t)4 * NB * 256 * 2;
    float* fm   = (float*)w; w += (size_t)NB * 4;
    float* gates= (float*)w; w += (size_t)NB * 12 * 4;
    float* part = (float*)w; w += (size_t)4 * NB * 3 * 4;

    k_pack<<<442, 256, 0, stream>>>(cW1, cW2, coW, expW1, expW2, gateW, wp);
    k_build<<<NB / 64, 256, 0, stream>>>(
        disc, cf, emb0, emb1, emb2, emb3, emb4, emb5, emb6, emb7,
        contW, contB, fmW, xpk, fm);
    k_c1<<<dim3(2, 128), 256, 0, stream>>>(wp, xpk, cb1, c1pk);
    k_c2<<<dim3(1, 128), 256, 0, stream>>>(wp, c1pk, cb2, c2pk);
    k_h <<<dim3(4, 128), 256, 0, stream>>>(wp, c2pk, cob, fm, xpk);
    k_e1<<<dim3(9, 128), 256, 0, stream>>>(wp, xpk, expb1, gateB, e1pk, gates);
    k_e2<<<dim3(1, 128, 4), 256, 0, stream>>>(wp, e1pk, expb2, taskW, gates, part);
    k_final<<<192, 256, 0, stream>>>(part, taskB, logv, (float*)d_out);
}